// Round 2
// baseline (37990.857 us; speedup 1.0000x reference)
//
#include <hip/hip_runtime.h>

typedef unsigned int u32;
typedef unsigned short u16;

#define T_STEPS 2048
#define BATCH   32
#define HID     512
#define INDIM   128
#define OUTD    128
#define NG      2048
#define L0_WGS  64
#define L1_WGS  64
#define FC_WGS  4
#define NWG     (L0_WGS + L1_WGS + FC_WGS)
#define BH      (BATCH * HID)

#define HID_OFF 8388608           // 32*2048*128
#define CN_OFF  8396800           // + 2*32*128

// ws layout (bytes)
#define WS_FLAGS   0                         // 132 flags, 64B stride (16 KB reserved)
#define WS_H0RING  16384
#define WS_H1RING  (WS_H0RING + 131072)      // 4*32*512*2
#define WS_BIAS0   (WS_H1RING + 131072)
#define WS_BIAS1   (WS_BIAS0 + 8192)
#define WS_WFC     (WS_BIAS1 + 8192)         // 4 * 16384 u16
#define WS_WL0     (WS_WFC + 131072)         // 64 * 20480 u16
#define WS_WL1     (WS_WL0 + 2621440)        // 64 * 32768 u16
#define WS_XBF     (WS_WL1 + 4194304)        // 32*2048*128 u16

typedef __bf16 bf16x8 __attribute__((ext_vector_type(8)));
typedef float  f32x4  __attribute__((ext_vector_type(4)));

__device__ __forceinline__ u16 f2bf(float f) {
    u32 u = __float_as_uint(f);
    u32 r = u + 0x7FFFu + ((u >> 16) & 1u);
    return (u16)(r >> 16);
}

union UB { uint4 u; bf16x8 b; };
__device__ __forceinline__ bf16x8 as_bf(uint4 u) { UB x; x.u = u; return x.b; }

__device__ __forceinline__ u32 relu2(u32 u) {
    u32 lo = (u & 0x8000u)     ? 0u : (u & 0xFFFFu);
    u32 hi = (u & 0x80000000u) ? 0u : (u & 0xFFFF0000u);
    return lo | hi;
}

// ---------------- prep kernels ----------------

__global__ void k_zero(u32* dst, int n) {
    int i = blockIdx.x * blockDim.x + threadIdx.x;
    if (i < n) dst[i] = 0u;
}

__global__ void k_bias(const float* __restrict__ bih0, const float* __restrict__ bhh0,
                       const float* __restrict__ bih1, const float* __restrict__ bhh1,
                       float* __restrict__ bias0, float* __restrict__ bias1) {
    int i = blockIdx.x * blockDim.x + threadIdx.x;
    if (i < NG) {
        int orig = (i & 3) * HID + (i >> 2);
        bias0[i] = bih0[orig] + bhh0[orig];
        bias1[i] = bih1[orig] + bhh1[orig];
    }
}

__global__ void k_xconv(const float* __restrict__ x, u16* __restrict__ xbf) {
    int i = blockIdx.x * blockDim.x + threadIdx.x;   // exactly 2097152 threads
    float4 v = reinterpret_cast<const float4*>(x)[i];
    u32 lo = (u32)f2bf(v.x) | ((u32)f2bf(v.y) << 16);
    u32 hi = (u32)f2bf(v.z) | ((u32)f2bf(v.w) << 16);
    reinterpret_cast<uint2*>(xbf)[i] = make_uint2(lo, hi);
}

// LDS-ready layout per WG: [ks][kb(4)][n(32)][8], value = W[p = wg*32+n][k = 32ks+8kb+j]
__global__ void k_wconv(const float* __restrict__ wih0, const float* __restrict__ whh0,
                        const float* __restrict__ wih1, const float* __restrict__ whh1,
                        const float* __restrict__ fcw,
                        u16* __restrict__ wl0, u16* __restrict__ wl1, u16* __restrict__ wfc) {
    int i = blockIdx.x * blockDim.x + threadIdx.x;   // exactly 3473408 threads
    if (i < 64 * 20480) {                            // layer0: K=640 (512 hh + 128 ih)
        int wg = i / 20480, r = i % 20480;
        int ks = r / 1024, kb = (r % 1024) / 256, n = (r % 256) / 8, j = r % 8;
        int k = ks * 32 + kb * 8 + j;
        int p = wg * 32 + n;
        int orig = (p & 3) * HID + (p >> 2);
        float v = (k < HID) ? whh0[orig * HID + k] : wih0[orig * INDIM + (k - HID)];
        wl0[i] = f2bf(v);
        return;
    }
    int i1 = i - 64 * 20480;
    if (i1 < 64 * 32768) {                           // layer1: K=1024 (512 ih(h0) + 512 hh(h1))
        int wg = i1 / 32768, r = i1 % 32768;
        int ks = r / 1024, kb = (r % 1024) / 256, n = (r % 256) / 8, j = r % 8;
        int k = ks * 32 + kb * 8 + j;
        int p = wg * 32 + n;
        int orig = (p & 3) * HID + (p >> 2);
        float v = (k < HID) ? wih1[orig * HID + k] : whh1[orig * HID + (k - HID)];
        wl1[i1] = f2bf(v);
        return;
    }
    int i2 = i1 - 64 * 32768;
    if (i2 < 4 * 16384) {                            // fc: K=512, no row permutation
        int wg = i2 / 16384, r = i2 % 16384;
        int ks = r / 1024, kb = (r % 1024) / 256, n = (r % 256) / 8, j = r % 8;
        int k = ks * 32 + kb * 8 + j;
        int o = wg * 32 + n;
        wfc[i2] = f2bf(fcw[o * HID + k]);
    }
}

// ---------------- persistent fused LSTM ----------------

__global__ __launch_bounds__(256, 1)
void k_lstm(const u16* __restrict__ xbf,
            const u16* __restrict__ wl0g, const u16* __restrict__ wl1g, const u16* __restrict__ wfcg,
            const float* __restrict__ bias0, const float* __restrict__ bias1, const float* __restrict__ fcb,
            u16* __restrict__ h0ring, u16* __restrict__ h1ring,
            u32* __restrict__ flags, float* __restrict__ dout)
{
    __shared__ u16 wlds[32768];                      // 64 KB
    const int tid  = threadIdx.x;
    const int lane = tid & 63;
    const int wv   = tid >> 6;
    const int mt   = wv >> 1;                        // batch-half tile
    const int nt   = wv & 1;                         // col tile
    const int ci   = lane & 15;
    const int quad = lane >> 4;
    const int wg   = blockIdx.x;

    int role, rwg;
    if      (wg < L0_WGS)           { role = 0; rwg = wg; }
    else if (wg < L0_WGS + L1_WGS)  { role = 1; rwg = wg - L0_WGS; }
    else                            { role = 2; rwg = wg - L0_WGS - L1_WGS; }

    u32* flagL0 = flags;
    u32* flagL1 = flags + 64 * 16;
    u32* flagFC = flags + 128 * 16;
    u32* myflag = flags + wg * 16;

    {   // stage this WG's weight slice into LDS (once)
        const u16* src = (role == 0) ? (wl0g + rwg * 20480)
                       : (role == 1) ? (wl1g + rwg * 32768)
                                     : (wfcg + rwg * 16384);
        const int n4 = (role == 0) ? 2560 : (role == 1) ? 4096 : 2048;
        uint4* d4 = reinterpret_cast<uint4*>(wlds);
        const uint4* s4 = reinterpret_cast<const uint4*>(src);
        for (int i = tid; i < n4; i += 256) d4[i] = s4[i];
    }
    __syncthreads();

    const bf16x8* wp = reinterpret_cast<const bf16x8*>(wlds);
    const int pcol   = rwg * 32 + nt * 16 + ci;      // permuted gate col (roles 0/1) or out col (fc)
    const int gateid = pcol & 3;                     // 0=i 1=f 2=g 3=o
    const float bias = (role == 0) ? bias0[pcol] : (role == 1) ? bias1[pcol] : fcb[pcol];
    const int brow0  = mt * 16 + quad * 4;           // C/D: batch of acc reg r is brow0+r
    const int arow   = mt * 16 + ci;                 // A-frag batch row
    const int jidx   = pcol >> 2;                    // h index owned (roles 0/1)

    float cst[4] = {0.f, 0.f, 0.f, 0.f};             // c-state, f32, replicated x4 lanes

    auto spin = [&](u32* f, int target) {
        if (target > 0)
            while ((int)__hip_atomic_load(f, __ATOMIC_RELAXED, __HIP_MEMORY_SCOPE_AGENT) < target)
                __builtin_amdgcn_s_sleep(1);
    };

    auto epi = [&](const f32x4& acc, u16* ringOut) {
        float ga[4], hv[4];
        #pragma unroll
        for (int r = 0; r < 4; ++r) {
            float g  = acc[r] + bias;
            float sv = 1.0f / (1.0f + __expf(-g));
            float tv = 1.0f - 2.0f / (__expf(2.0f * g) + 1.0f);
            ga[r] = (gateid == 2) ? tv : sv;
        }
        const int bl = lane & ~3;
        #pragma unroll
        for (int r = 0; r < 4; ++r) {
            float iv = __shfl(ga[r], bl + 0);
            float fv = __shfl(ga[r], bl + 1);
            float gv = __shfl(ga[r], bl + 2);
            float ov = __shfl(ga[r], bl + 3);
            float cn = fv * cst[r] + iv * gv;
            cst[r] = cn;
            hv[r] = ov * (1.0f - 2.0f / (__expf(2.0f * cn) + 1.0f));
        }
        if ((ci & 3) == 0) {
            #pragma unroll
            for (int r = 0; r < 4; ++r)                // agent-scope write-through: lands in LLC,
                __hip_atomic_store(&ringOut[(brow0 + r) * HID + jidx], f2bf(hv[r]),
                                   __ATOMIC_RELAXED, __HIP_MEMORY_SCOPE_AGENT);
        }
    };

    auto fcTile = [&](const u16* aRow) -> f32x4 {
        f32x4 a = {0.f, 0.f, 0.f, 0.f};
        #pragma unroll
        for (int ks = 0; ks < 16; ++ks) {
            uint4 av = *reinterpret_cast<const uint4*>(aRow + ks * 32);
            av.x = relu2(av.x); av.y = relu2(av.y); av.z = relu2(av.z); av.w = relu2(av.w);
            bf16x8 bv = wp[(ks * 4 + quad) * 32 + nt * 16 + ci];
            a = __builtin_amdgcn_mfma_f32_16x16x32_bf16(as_bf(av), bv, a, 0, 0, 0);
        }
        return a;
    };

    if (role == 0) {
        u32* pf = (tid < 64) ? (flagL0 + tid * 16) : (tid < 128) ? (flagL1 + (tid - 64) * 16) : nullptr;
        const int po = (tid < 64) ? 0 : -3;
        for (int t = 0; t < T_STEPS; ++t) {
            // x-part MFMAs don't depend on h: do them before the wait
            const u16* xA = xbf + (arow * T_STEPS + t) * INDIM + quad * 8;
            f32x4 acc = {0.f, 0.f, 0.f, 0.f};
            uint4 xv[4];
            #pragma unroll
            for (int k4 = 0; k4 < 4; ++k4) xv[k4] = *reinterpret_cast<const uint4*>(xA + k4 * 32);
            #pragma unroll
            for (int k4 = 0; k4 < 4; ++k4) {
                bf16x8 bv = wp[((16 + k4) * 4 + quad) * 32 + nt * 16 + ci];
                acc = __builtin_amdgcn_mfma_f32_16x16x32_bf16(as_bf(xv[k4]), bv, acc, 0, 0, 0);
            }
            if (pf) spin(pf, t + po);
            __syncthreads();
            __threadfence();                          // acquire
            const u16* hA = h0ring + ((t + 3) & 3) * BH + arow * HID + quad * 8;
            #pragma unroll
            for (int ks = 0; ks < 16; ++ks) {
                uint4 av = *reinterpret_cast<const uint4*>(hA + ks * 32);
                bf16x8 bv = wp[(ks * 4 + quad) * 32 + nt * 16 + ci];
                acc = __builtin_amdgcn_mfma_f32_16x16x32_bf16(as_bf(av), bv, acc, 0, 0, 0);
            }
            epi(acc, h0ring + (t & 3) * BH);
            __threadfence();                          // release
            __syncthreads();
            if (tid == 0)
                __hip_atomic_store(myflag, (u32)(t + 1), __ATOMIC_RELAXED, __HIP_MEMORY_SCOPE_AGENT);
        }
    } else if (role == 1) {
        u32* pf = (tid < 64)  ? (flagL0 + tid * 16)
                : (tid < 128) ? (flagL1 + (tid - 64) * 16)
                : (tid < 132) ? (flagFC + (tid - 128) * 16) : nullptr;
        const int po = (tid < 64) ? 1 : (tid < 128) ? 0 : -3;
        for (int t = 0; t < T_STEPS; ++t) {
            if (pf) spin(pf, t + po);
            __syncthreads();
            __threadfence();                          // acquire
            const u16* h0A = h0ring + (t & 3) * BH + arow * HID + quad * 8;
            const u16* h1A = h1ring + ((t + 3) & 3) * BH + arow * HID + quad * 8;
            f32x4 acc = {0.f, 0.f, 0.f, 0.f};
            #pragma unroll
            for (int ks = 0; ks < 16; ++ks) {         // K 0..511: h0[t] (W_ih1)
                uint4 av = *reinterpret_cast<const uint4*>(h0A + ks * 32);
                bf16x8 bv = wp[(ks * 4 + quad) * 32 + nt * 16 + ci];
                acc = __builtin_amdgcn_mfma_f32_16x16x32_bf16(as_bf(av), bv, acc, 0, 0, 0);
            }
            #pragma unroll
            for (int ks = 16; ks < 32; ++ks) {        // K 512..1023: h1[t-1] (W_hh1)
                uint4 av = *reinterpret_cast<const uint4*>(h1A + (ks - 16) * 32);
                bf16x8 bv = wp[(ks * 4 + quad) * 32 + nt * 16 + ci];
                acc = __builtin_amdgcn_mfma_f32_16x16x32_bf16(as_bf(av), bv, acc, 0, 0, 0);
            }
            epi(acc, h1ring + (t & 3) * BH);
            __threadfence();                          // release
            __syncthreads();
            if (tid == 0)
                __hip_atomic_store(myflag, (u32)(t + 1), __ATOMIC_RELAXED, __HIP_MEMORY_SCOPE_AGENT);
        }
    } else {
        u32* pf = (tid < 64) ? (flagL1 + tid * 16) : nullptr;
        for (int t = 0; t < T_STEPS; ++t) {
            if (pf) spin(pf, t + 1);
            __syncthreads();
            __threadfence();                          // acquire
            const u16* h1A = h1ring + (t & 3) * BH + arow * HID + quad * 8;
            f32x4 acc = fcTile(h1A);
            #pragma unroll
            for (int r = 0; r < 4; ++r)
                dout[((brow0 + r) * T_STEPS + t) * OUTD + pcol] = acc[r] + bias;
            __syncthreads();                          // all reads of slot done before flag
            if (tid == 0)                             // reads need no release fence
                __hip_atomic_store(myflag, (u32)(t + 1), __ATOMIC_RELAXED, __HIP_MEMORY_SCOPE_AGENT);
        }
        // hidden = fc(relu(h_n)); h[T-1] lives in slot 3 of each ring
        for (int l = 0; l < 2; ++l) {
            const u16* aR = (l == 0 ? h0ring : h1ring) + 3 * BH + arow * HID + quad * 8;
            f32x4 hh = fcTile(aR);
            #pragma unroll
            for (int r = 0; r < 4; ++r)
                dout[HID_OFF + (l * BATCH + brow0 + r) * OUTD + pcol] = hh[r] + bias;
        }
    }

    // c_n output [2, 32, 512]
    if (role <= 1 && (ci & 3) == 0) {
        #pragma unroll
        for (int r = 0; r < 4; ++r)
            dout[CN_OFF + (role * BATCH + brow0 + r) * HID + jidx] = cst[r];
    }
}

// ---------------- launch ----------------

extern "C" void kernel_launch(void* const* d_in, const int* in_sizes, int n_in,
                              void* d_out, int out_size, void* d_ws, size_t ws_size,
                              hipStream_t stream) {
    const float* x    = (const float*)d_in[0];
    const float* wih0 = (const float*)d_in[1];
    const float* whh0 = (const float*)d_in[2];
    const float* bih0 = (const float*)d_in[3];
    const float* bhh0 = (const float*)d_in[4];
    const float* wih1 = (const float*)d_in[5];
    const float* whh1 = (const float*)d_in[6];
    const float* bih1 = (const float*)d_in[7];
    const float* bhh1 = (const float*)d_in[8];
    const float* fcw  = (const float*)d_in[9];
    const float* fcb  = (const float*)d_in[10];

    char* ws = (char*)d_ws;
    u32*  flags = (u32*)(ws + WS_FLAGS);
    u16*  h0r   = (u16*)(ws + WS_H0RING);
    u16*  h1r   = (u16*)(ws + WS_H1RING);
    float* b0   = (float*)(ws + WS_BIAS0);
    float* b1   = (float*)(ws + WS_BIAS1);
    u16*  wfc   = (u16*)(ws + WS_WFC);
    u16*  wl0   = (u16*)(ws + WS_WL0);
    u16*  wl1   = (u16*)(ws + WS_WL1);
    u16*  xbf   = (u16*)(ws + WS_XBF);
    float* dout = (float*)d_out;

    // zero flags + h rings (ws is re-poisoned before every timed call)
    k_zero<<<272, 256, 0, stream>>>((u32*)ws, 69632);
    k_bias<<<8, 256, 0, stream>>>(bih0, bhh0, bih1, bhh1, b0, b1);
    k_xconv<<<8192, 256, 0, stream>>>(x, xbf);
    k_wconv<<<13568, 256, 0, stream>>>(wih0, whh0, wih1, whh1, fcw, wl0, wl1, wfc);
    k_lstm<<<NWG, 256, 0, stream>>>(xbf, wl0, wl1, wfc, b0, b1, fcb,
                                    h0r, h1r, flags, dout);
}

// Round 4
// 18114.795 us; speedup vs baseline: 2.0972x; 2.0972x over previous
//
#include <hip/hip_runtime.h>

typedef unsigned int u32;
typedef unsigned short u16;
typedef unsigned long long u64;

#define T_STEPS 2048
#define BATCH   32
#define HID     512
#define INDIM   128
#define OUTD    128
#define NG      2048
#define L0_WGS  64
#define L1_WGS  64
#define FC_WGS  4
#define NWG     (L0_WGS + L1_WGS + FC_WGS)
#define BH      (BATCH * HID)

#define HID_OFF 8388608           // 32*2048*128
#define CN_OFF  8396800           // + 2*32*128

// ws layout (bytes)
#define WS_FLAGS   0                         // 132 flags, 64B stride (16 KB reserved)
#define WS_H0RING  16384
#define WS_H1RING  (WS_H0RING + 131072)      // 4*32*512*2
#define WS_BIAS0   (WS_H1RING + 131072)
#define WS_BIAS1   (WS_BIAS0 + 8192)
#define WS_WFC     (WS_BIAS1 + 8192)         // 4 * 16384 u16
#define WS_WL0     (WS_WFC + 131072)         // 64 * 20480 u16
#define WS_WL1     (WS_WL0 + 2621440)        // 64 * 32768 u16
#define WS_XBF     (WS_WL1 + 4194304)        // 32*2048*128 u16

typedef __bf16 bf16x8 __attribute__((ext_vector_type(8)));
typedef float  f32x4  __attribute__((ext_vector_type(4)));
typedef unsigned int u32x4 __attribute__((ext_vector_type(4)));

__device__ __forceinline__ u16 f2bf(float f) {
    u32 u = __float_as_uint(f);
    u32 r = u + 0x7FFFu + ((u >> 16) & 1u);
    return (u16)(r >> 16);
}

union UB2 { u32x4 u; bf16x8 b; };
__device__ __forceinline__ bf16x8 as_bf(u32x4 u) { UB2 x; x.u = u; return x.b; }

__device__ __forceinline__ u32 relu2(u32 u) {
    u32 lo = (u & 0x8000u)     ? 0u : (u & 0xFFFFu);
    u32 hi = (u & 0x80000000u) ? 0u : (u & 0xFFFF0000u);
    return lo | hi;
}

// LLC-coherent 16B load via two compiler-tracked agent-scope atomic loads.
// Lowered to global_load_dwordx2 sc0 sc1; compiler inserts vmcnt waits before use.
union U64X2 { u64 q[2]; u32x4 v; };
__device__ __forceinline__ u32x4 load_llc(const u16* p) {
    u64* q = (u64*)p;
    U64X2 r;
    r.q[0] = __hip_atomic_load(q + 0, __ATOMIC_RELAXED, __HIP_MEMORY_SCOPE_AGENT);
    r.q[1] = __hip_atomic_load(q + 1, __ATOMIC_RELAXED, __HIP_MEMORY_SCOPE_AGENT);
    return r.v;
}
__device__ __forceinline__ void vm0() {          // drain own stores to coherence point
    asm volatile("s_waitcnt vmcnt(0)" ::: "memory");
}

// ---------------- prep kernels ----------------

__global__ void k_zero(u32* dst, int n) {
    int i = blockIdx.x * blockDim.x + threadIdx.x;
    if (i < n) dst[i] = 0u;
}

__global__ void k_bias(const float* __restrict__ bih0, const float* __restrict__ bhh0,
                       const float* __restrict__ bih1, const float* __restrict__ bhh1,
                       float* __restrict__ bias0, float* __restrict__ bias1) {
    int i = blockIdx.x * blockDim.x + threadIdx.x;
    if (i < NG) {
        int orig = (i & 3) * HID + (i >> 2);
        bias0[i] = bih0[orig] + bhh0[orig];
        bias1[i] = bih1[orig] + bhh1[orig];
    }
}

__global__ void k_xconv(const float* __restrict__ x, u16* __restrict__ xbf) {
    int i = blockIdx.x * blockDim.x + threadIdx.x;   // exactly 2097152 threads
    float4 v = reinterpret_cast<const float4*>(x)[i];
    u32 lo = (u32)f2bf(v.x) | ((u32)f2bf(v.y) << 16);
    u32 hi = (u32)f2bf(v.z) | ((u32)f2bf(v.w) << 16);
    reinterpret_cast<uint2*>(xbf)[i] = make_uint2(lo, hi);
}

// LDS-ready layout per WG: [ks][kb(4)][n(32)][8], value = W[p = wg*32+n][k = 32ks+8kb+j]
__global__ void k_wconv(const float* __restrict__ wih0, const float* __restrict__ whh0,
                        const float* __restrict__ wih1, const float* __restrict__ whh1,
                        const float* __restrict__ fcw,
                        u16* __restrict__ wl0, u16* __restrict__ wl1, u16* __restrict__ wfc) {
    int i = blockIdx.x * blockDim.x + threadIdx.x;   // exactly 3473408 threads
    if (i < 64 * 20480) {                            // layer0: K=640 (512 hh + 128 ih)
        int wg = i / 20480, r = i % 20480;
        int ks = r / 1024, kb = (r % 1024) / 256, n = (r % 256) / 8, j = r % 8;
        int k = ks * 32 + kb * 8 + j;
        int p = wg * 32 + n;
        int orig = (p & 3) * HID + (p >> 2);
        float v = (k < HID) ? whh0[orig * HID + k] : wih0[orig * INDIM + (k - HID)];
        wl0[i] = f2bf(v);
        return;
    }
    int i1 = i - 64 * 20480;
    if (i1 < 64 * 32768) {                           // layer1: K=1024 (512 ih(h0) + 512 hh(h1))
        int wg = i1 / 32768, r = i1 % 32768;
        int ks = r / 1024, kb = (r % 1024) / 256, n = (r % 256) / 8, j = r % 8;
        int k = ks * 32 + kb * 8 + j;
        int p = wg * 32 + n;
        int orig = (p & 3) * HID + (p >> 2);
        float v = (k < HID) ? wih1[orig * HID + k] : whh1[orig * HID + (k - HID)];
        wl1[i1] = f2bf(v);
        return;
    }
    int i2 = i1 - 64 * 32768;
    if (i2 < 4 * 16384) {                            // fc: K=512, no row permutation
        int wg = i2 / 16384, r = i2 % 16384;
        int ks = r / 1024, kb = (r % 1024) / 256, n = (r % 256) / 8, j = r % 8;
        int k = ks * 32 + kb * 8 + j;
        int o = wg * 32 + n;
        wfc[i2] = f2bf(fcw[o * HID + k]);
    }
}

// ---------------- persistent fused LSTM ----------------

__global__ __launch_bounds__(256, 1)
void k_lstm(const u16* __restrict__ xbf,
            const u16* __restrict__ wl0g, const u16* __restrict__ wl1g, const u16* __restrict__ wfcg,
            const float* __restrict__ bias0, const float* __restrict__ bias1, const float* __restrict__ fcb,
            u16* __restrict__ h0ring, u16* __restrict__ h1ring,
            u32* __restrict__ flags, float* __restrict__ dout)
{
    __shared__ u16 wlds[32768];                      // 64 KB
    const int tid  = threadIdx.x;
    const int lane = tid & 63;
    const int wv   = tid >> 6;
    const int mt   = wv >> 1;                        // batch-half tile
    const int nt   = wv & 1;                         // col tile
    const int ci   = lane & 15;
    const int quad = lane >> 4;
    const int wg   = blockIdx.x;

    int role, rwg;
    if      (wg < L0_WGS)           { role = 0; rwg = wg; }
    else if (wg < L0_WGS + L1_WGS)  { role = 1; rwg = wg - L0_WGS; }
    else                            { role = 2; rwg = wg - L0_WGS - L1_WGS; }

    u32* flagL0 = flags;
    u32* flagL1 = flags + 64 * 16;
    u32* flagFC = flags + 128 * 16;
    u32* myflag = flags + wg * 16;

    {   // stage this WG's weight slice into LDS (once)
        const u16* src = (role == 0) ? (wl0g + rwg * 20480)
                       : (role == 1) ? (wl1g + rwg * 32768)
                                     : (wfcg + rwg * 16384);
        const int n4 = (role == 0) ? 2560 : (role == 1) ? 4096 : 2048;
        uint4* d4 = reinterpret_cast<uint4*>(wlds);
        const uint4* s4 = reinterpret_cast<const uint4*>(src);
        for (int i = tid; i < n4; i += 256) d4[i] = s4[i];
    }
    __syncthreads();

    const bf16x8* wp = reinterpret_cast<const bf16x8*>(wlds);
    const int pcol   = rwg * 32 + nt * 16 + ci;      // permuted gate col (roles 0/1) or out col (fc)
    const int gateid = pcol & 3;                     // 0=i 1=f 2=g 3=o
    const float bias = (role == 0) ? bias0[pcol] : (role == 1) ? bias1[pcol] : fcb[pcol];
    const int brow0  = mt * 16 + quad * 4;           // C/D: batch of acc reg r is brow0+r
    const int arow   = mt * 16 + ci;                 // A-frag batch row
    const int jidx   = pcol >> 2;                    // h index owned (roles 0/1)

    float cst[4] = {0.f, 0.f, 0.f, 0.f};             // c-state, f32, replicated x4 lanes

    auto spin = [&](u32* f, int target) {
        if (target > 0)
            while ((int)__hip_atomic_load(f, __ATOMIC_RELAXED, __HIP_MEMORY_SCOPE_AGENT) < target)
                __builtin_amdgcn_s_sleep(1);
    };

    auto epi = [&](const f32x4& acc, u16* ringOut) {
        float ga[4], hv[4];
        #pragma unroll
        for (int r = 0; r < 4; ++r) {
            float g  = acc[r] + bias;
            float sv = 1.0f / (1.0f + __expf(-g));
            float tv = 1.0f - 2.0f / (__expf(2.0f * g) + 1.0f);
            ga[r] = (gateid == 2) ? tv : sv;
        }
        const int bl = lane & ~3;
        #pragma unroll
        for (int r = 0; r < 4; ++r) {
            float iv = __shfl(ga[r], bl + 0);
            float fv = __shfl(ga[r], bl + 1);
            float gv = __shfl(ga[r], bl + 2);
            float ov = __shfl(ga[r], bl + 3);
            float cn = fv * cst[r] + iv * gv;
            cst[r] = cn;
            hv[r] = ov * (1.0f - 2.0f / (__expf(2.0f * cn) + 1.0f));
        }
        if ((ci & 3) == 0) {
            #pragma unroll
            for (int r = 0; r < 4; ++r)                // agent-scope write-through: lands in LLC
                __hip_atomic_store(&ringOut[(brow0 + r) * HID + jidx], f2bf(hv[r]),
                                   __ATOMIC_RELAXED, __HIP_MEMORY_SCOPE_AGENT);
        }
    };

    auto fcTile = [&](const u16* aRow) -> f32x4 {
        u32x4 av[16];
        #pragma unroll
        for (int ks = 0; ks < 16; ++ks) av[ks] = load_llc(aRow + ks * 32);
        f32x4 a = {0.f, 0.f, 0.f, 0.f};
        #pragma unroll
        for (int ks = 0; ks < 16; ++ks) {
            u32x4 v = av[ks];
            v[0] = relu2(v[0]); v[1] = relu2(v[1]); v[2] = relu2(v[2]); v[3] = relu2(v[3]);
            bf16x8 bv = wp[(ks * 4 + quad) * 32 + nt * 16 + ci];
            a = __builtin_amdgcn_mfma_f32_16x16x32_bf16(as_bf(v), bv, a, 0, 0, 0);
        }
        return a;
    };

    if (role == 0) {
        u32* pf = (tid < 64) ? (flagL0 + tid * 16) : (tid < 128) ? (flagL1 + (tid - 64) * 16) : nullptr;
        const int po = (tid < 64) ? 0 : -3;
        for (int t = 0; t < T_STEPS; ++t) {
            // x-part MFMAs don't depend on h: do them before the wait (normal cached loads)
            const u16* xA = xbf + (arow * T_STEPS + t) * INDIM + quad * 8;
            f32x4 acc = {0.f, 0.f, 0.f, 0.f};
            u32x4 xv[4];
            #pragma unroll
            for (int k4 = 0; k4 < 4; ++k4) xv[k4] = *reinterpret_cast<const u32x4*>(xA + k4 * 32);
            #pragma unroll
            for (int k4 = 0; k4 < 4; ++k4) {
                bf16x8 bv = wp[((16 + k4) * 4 + quad) * 32 + nt * 16 + ci];
                acc = __builtin_amdgcn_mfma_f32_16x16x32_bf16(as_bf(xv[k4]), bv, acc, 0, 0, 0);
            }
            if (pf) spin(pf, t + po);
            __syncthreads();
            const u16* hA = h0ring + ((t + 3) & 3) * BH + arow * HID + quad * 8;
            u32x4 hvv[16];
            #pragma unroll
            for (int ks = 0; ks < 16; ++ks) hvv[ks] = load_llc(hA + ks * 32);
            #pragma unroll
            for (int ks = 0; ks < 16; ++ks) {
                bf16x8 bv = wp[(ks * 4 + quad) * 32 + nt * 16 + ci];
                acc = __builtin_amdgcn_mfma_f32_16x16x32_bf16(as_bf(hvv[ks]), bv, acc, 0, 0, 0);
            }
            epi(acc, h0ring + (t & 3) * BH);
            vm0();                                    // h stores complete at LLC
            __syncthreads();
            if (tid == 0)
                __hip_atomic_store(myflag, (u32)(t + 1), __ATOMIC_RELAXED, __HIP_MEMORY_SCOPE_AGENT);
        }
    } else if (role == 1) {
        u32* pf = (tid < 64)  ? (flagL0 + tid * 16)
                : (tid < 128) ? (flagL1 + (tid - 64) * 16)
                : (tid < 132) ? (flagFC + (tid - 128) * 16) : nullptr;
        const int po = (tid < 64) ? 1 : (tid < 128) ? 0 : -3;
        for (int t = 0; t < T_STEPS; ++t) {
            if (pf) spin(pf, t + po);
            __syncthreads();
            const u16* h0A = h0ring + (t & 3) * BH + arow * HID + quad * 8;
            const u16* h1A = h1ring + ((t + 3) & 3) * BH + arow * HID + quad * 8;
            u32x4 h0v[16], h1v[16];
            #pragma unroll
            for (int ks = 0; ks < 16; ++ks) h0v[ks] = load_llc(h0A + ks * 32);
            #pragma unroll
            for (int ks = 0; ks < 16; ++ks) h1v[ks] = load_llc(h1A + ks * 32);
            f32x4 acc = {0.f, 0.f, 0.f, 0.f};
            #pragma unroll
            for (int ks = 0; ks < 16; ++ks) {         // K 0..511: h0[t] (W_ih1)
                bf16x8 bv = wp[(ks * 4 + quad) * 32 + nt * 16 + ci];
                acc = __builtin_amdgcn_mfma_f32_16x16x32_bf16(as_bf(h0v[ks]), bv, acc, 0, 0, 0);
            }
            #pragma unroll
            for (int ks = 16; ks < 32; ++ks) {        // K 512..1023: h1[t-1] (W_hh1)
                bf16x8 bv = wp[(ks * 4 + quad) * 32 + nt * 16 + ci];
                acc = __builtin_amdgcn_mfma_f32_16x16x32_bf16(as_bf(h1v[ks - 16]), bv, acc, 0, 0, 0);
            }
            epi(acc, h1ring + (t & 3) * BH);
            vm0();                                    // h stores complete at LLC
            __syncthreads();
            if (tid == 0)
                __hip_atomic_store(myflag, (u32)(t + 1), __ATOMIC_RELAXED, __HIP_MEMORY_SCOPE_AGENT);
        }
    } else {
        u32* pf = (tid < 64) ? (flagL1 + tid * 16) : nullptr;
        for (int t = 0; t < T_STEPS; ++t) {
            if (pf) spin(pf, t + 1);
            __syncthreads();
            const u16* h1A = h1ring + (t & 3) * BH + arow * HID + quad * 8;
            f32x4 acc = fcTile(h1A);
            #pragma unroll
            for (int r = 0; r < 4; ++r)
                dout[((brow0 + r) * T_STEPS + t) * OUTD + pcol] = acc[r] + bias;
            __syncthreads();                          // all reads of slot done before flag
            if (tid == 0)                             // reads complete before their MFMA uses
                __hip_atomic_store(myflag, (u32)(t + 1), __ATOMIC_RELAXED, __HIP_MEMORY_SCOPE_AGENT);
        }
        // hidden = fc(relu(h_n)); h[T-1] lives in slot 3 of each ring (2047 & 3 == 3)
        for (int l = 0; l < 2; ++l) {
            const u16* aR = (l == 0 ? h0ring : h1ring) + 3 * BH + arow * HID + quad * 8;
            f32x4 hh = fcTile(aR);
            #pragma unroll
            for (int r = 0; r < 4; ++r)
                dout[HID_OFF + (l * BATCH + brow0 + r) * OUTD + pcol] = hh[r] + bias;
        }
    }

    // c_n output [2, 32, 512]
    if (role <= 1 && (ci & 3) == 0) {
        #pragma unroll
        for (int r = 0; r < 4; ++r)
            dout[CN_OFF + (role * BATCH + brow0 + r) * HID + jidx] = cst[r];
    }
}

// ---------------- launch ----------------

extern "C" void kernel_launch(void* const* d_in, const int* in_sizes, int n_in,
                              void* d_out, int out_size, void* d_ws, size_t ws_size,
                              hipStream_t stream) {
    const float* x    = (const float*)d_in[0];
    const float* wih0 = (const float*)d_in[1];
    const float* whh0 = (const float*)d_in[2];
    const float* bih0 = (const float*)d_in[3];
    const float* bhh0 = (const float*)d_in[4];
    const float* wih1 = (const float*)d_in[5];
    const float* whh1 = (const float*)d_in[6];
    const float* bih1 = (const float*)d_in[7];
    const float* bhh1 = (const float*)d_in[8];
    const float* fcw  = (const float*)d_in[9];
    const float* fcb  = (const float*)d_in[10];

    char* ws = (char*)d_ws;
    u32*  flags = (u32*)(ws + WS_FLAGS);
    u16*  h0r   = (u16*)(ws + WS_H0RING);
    u16*  h1r   = (u16*)(ws + WS_H1RING);
    float* b0   = (float*)(ws + WS_BIAS0);
    float* b1   = (float*)(ws + WS_BIAS1);
    u16*  wfc   = (u16*)(ws + WS_WFC);
    u16*  wl0   = (u16*)(ws + WS_WL0);
    u16*  wl1   = (u16*)(ws + WS_WL1);
    u16*  xbf   = (u16*)(ws + WS_XBF);
    float* dout = (float*)d_out;

    // zero flags + h rings (ws is re-poisoned before every timed call)
    k_zero<<<272, 256, 0, stream>>>((u32*)ws, 69632);
    k_bias<<<8, 256, 0, stream>>>(bih0, bhh0, bih1, bhh1, b0, b1);
    k_xconv<<<8192, 256, 0, stream>>>(x, xbf);
    k_wconv<<<13568, 256, 0, stream>>>(wih0, whh0, wih1, whh1, fcw, wl0, wl1, wfc);
    k_lstm<<<NWG, 256, 0, stream>>>(xbf, wl0, wl1, wfc, b0, b1, fcb,
                                    h0r, h1r, flags, dout);
}